// Round 11
// baseline (408.765 us; speedup 1.0000x reference)
//
#include <hip/hip_runtime.h>
#include <stdint.h>

#define NTHREADS 256
#define KTOP 50
#define CAP 1024
#define EPSV 1e-8f

typedef unsigned long long u64;
typedef uint32_t u32;
typedef float __attribute__((ext_vector_type(4))) f4;

// s_c: 0=cntP 1=cntQ 2=ovfl 3=fallback counter
#define C_CNTP 0
#define C_CNTQ 1
#define C_OVF  2
#define C_GEN  3

// ---- block-wide float max ----
__device__ __forceinline__ float block_max(float v, float* s_f, int tid) {
    for (int off = 32; off; off >>= 1) v = fmaxf(v, __shfl_down(v, off));
    if ((tid & 63) == 0) s_f[tid >> 6] = v;
    __syncthreads();
    if (tid == 0) {
        float m = s_f[0];
        for (int w = 1; w < NTHREADS / 64; ++w) m = fmaxf(m, s_f[w]);
        s_f[4] = m;
    }
    __syncthreads();
    float r = s_f[4];
    __syncthreads();
    return r;
}

// ---- u32-key push: key = (bits(v)-bits(t))<<16 | (0xFFFF-idx) ----
__device__ __forceinline__ void push32(u32* cand, u32* cnt, u32* ovf,
                                       float v, int idx, float t, u32 tbits) {
    if (v >= t) {
        u32 delta = __float_as_uint(v) - tbits;
        if (delta > 0xFFFFu) { *ovf = 1u; delta = 0xFFFFu; }
        u32 pos = atomicAdd(cnt, 1u);
        if (pos < CAP) cand[pos] = (delta << 16) | (0xFFFFu - (u32)idx);
    }
}

// ---- u64 push (validated fallback path) ----
__device__ __forceinline__ void push64(u64* cand, u32* cnt,
                                       float v, int idx, float t) {
    if (v >= t) {
        u32 pos = atomicAdd(cnt, 1u);
        if (pos < CAP)
            cand[pos] = (((u64)__float_as_uint(v)) << 16) |
                        (u64)(0xFFFFu - (u32)idx);
    }
}

// ---- cold path: per-element direct u64 collect (validated R2-R10) ----
__device__ int collect_direct64(const float* __restrict__ row, int V, float t,
                                u64* cand, u32* s_cnt, int tid) {
    if (tid == 0) *s_cnt = 0;
    __syncthreads();
    int mis = (int)(((uintptr_t)row >> 2) & 3);
    int head = (4 - mis) & 3; if (head > V) head = V;
    if (tid < head) push64(cand, s_cnt, row[tid], tid, t);
    int nvec = (V - head) >> 2;
    const float4* vr = reinterpret_cast<const float4*>(row + head);
    for (int i = tid; i < nvec; i += NTHREADS) {
        float4 v = vr[i];
        int b = head + (i << 2);
        push64(cand, s_cnt, v.x, b, t);     push64(cand, s_cnt, v.y, b + 1, t);
        push64(cand, s_cnt, v.z, b + 2, t); push64(cand, s_cnt, v.w, b + 3, t);
    }
    for (int i = head + (nvec << 2) + tid; i < V; i += NTHREADS)
        push64(cand, s_cnt, row[i], i, t);
    __syncthreads();
    int n = (int)*s_cnt;
    __syncthreads();
    return n;
}

// ---- u64 two-phase find_topk (validated fallback) ----
__device__ void find_topk64(const u64* cand, int nc, uint16_t* top,
                            u64* s_merge, int tid) {
    int lane = tid & 63, w = tid >> 6;
    u64 r0 = 0, r1 = 0, r2 = 0, r3 = 0;
    int j0 = (w << 6) + lane;
    if (j0 < nc)       r0 = cand[j0];
    if (j0 + 256 < nc) r1 = cand[j0 + 256];
    if (j0 + 512 < nc) r2 = cand[j0 + 512];
    if (j0 + 768 < nc) r3 = cand[j0 + 768];
    for (int k = 0; k < KTOP; ++k) {
        u64 a = r0 > r1 ? r0 : r1;
        u64 b = r2 > r3 ? r2 : r3;
        u64 m = a > b ? a : b;
        #pragma unroll
        for (int off = 32; off; off >>= 1) {
            u64 o = __shfl_xor(m, off);
            if (o > m) m = o;
        }
        if (lane == 0) s_merge[w * KTOP + k] = m;
        if (r0 == m) r0 = 0; else if (r1 == m) r1 = 0;
        else if (r2 == m) r2 = 0; else if (r3 == m) r3 = 0;
    }
    __syncthreads();
    if (w == 0) {
        u64 q0 = 0, q1 = 0, q2 = 0, q3 = 0;
        if (lane < 4 * KTOP)       q0 = s_merge[lane];
        if (lane + 64 < 4 * KTOP)  q1 = s_merge[lane + 64];
        if (lane + 128 < 4 * KTOP) q2 = s_merge[lane + 128];
        if (lane + 192 < 4 * KTOP) q3 = s_merge[lane + 192];
        for (int k = 0; k < KTOP; ++k) {
            u64 a = q0 > q1 ? q0 : q1;
            u64 b = q2 > q3 ? q2 : q3;
            u64 m = a > b ? a : b;
            #pragma unroll
            for (int off = 32; off; off >>= 1) {
                u64 o = __shfl_xor(m, off);
                if (o > m) m = o;
            }
            if (lane == 0) top[k] = (uint16_t)(0xFFFFu - (u32)(m & 0xFFFFu));
            if (q0 == m) q0 = 0; else if (q1 == m) q1 = 0;
            else if (q2 == m) q2 = 0; else if (q3 == m) q3 = 0;
        }
    }
    __syncthreads();
}

// ---- single-wave u32 top-50: zero barriers, non-destructive LDS reads ----
template <int NR>
__device__ void find32(const u32* cand, int nc, uint16_t* top, int lane) {
    u32 r[NR];
    #pragma unroll
    for (int j = 0; j < NR; ++j) {
        int idx = lane + j * 64;
        r[j] = (idx < nc) ? cand[idx] : 0u;
    }
    u32 mine = 0;
    for (int k = 0; k < KTOP; ++k) {
        u32 m = 0;
        #pragma unroll
        for (int j = 0; j < NR; ++j) m = r[j] > m ? r[j] : m;
        #pragma unroll
        for (int off = 32; off; off >>= 1) {
            u32 o = __shfl_xor(m, off);
            m = o > m ? o : m;
        }
        if (lane == k) mine = m;
        #pragma unroll
        for (int j = 0; j < NR; ++j) if (r[j] == m) r[j] = 0;
    }
    if (lane < KTOP) top[lane] = (uint16_t)(0xFFFFu - (mine & 0xFFFFu));
}

// ---- inline-asm single load: opaque to compiler, counted manually ----
#define ISSUE1(R, PTR) \
    asm volatile("global_load_dwordx4 %0, %1, off" \
                 : "=&v"(R) : "v"(PTR))

// counted wait: oldest load complete, rest in flight; fence hoisting
#define WAITV(N) do { \
    asm volatile("s_waitcnt vmcnt(" #N ")" ::: "memory"); \
    __builtin_amdgcn_sched_barrier(0); } while (0)

#define CONSUME1(R, G) do { \
    float _m = fmaxf(fmaxf(R.x, R.y), fmaxf(R.z, R.w)); \
    if (_m >= t) { \
        int _e = head + (((G) * NTHREADS + tid) << 2); \
        push32(cand, cnt, ovf, R.x, _e,     t, tbits); \
        push32(cand, cnt, ovf, R.y, _e + 1, t, tbits); \
        push32(cand, cnt, ovf, R.z, _e + 2, t, tbits); \
        push32(cand, cnt, ovf, R.w, _e + 3, t, tbits); \
    } } while (0)

// ---- one full streaming pass over a row: 6-slot ring, 6 loads in flight ----
__device__ __forceinline__ void stream_one(
    const float* __restrict__ row, int V, float t, u32 tbits,
    u32* cand, u32* cnt, u32* ovf, int tid)
{
    int mis = (int)(((uintptr_t)row >> 2) & 3);
    int head = (4 - mis) & 3; if (head > V) head = V;
    int nvec = (V - head) >> 2;
    const f4* v4 = reinterpret_cast<const f4*>(row + head);

    if (tid < head) push32(cand, cnt, ovf, row[tid], tid, t, tbits);

    int ngrp = nvec / NTHREADS;
    int ring = 0;
    if (ngrp >= 12) {
        f4 s0, s1, s2, s3, s4, s5;
        const f4* pp = v4 + tid;
        ISSUE1(s0, pp); pp += NTHREADS;
        ISSUE1(s1, pp); pp += NTHREADS;
        ISSUE1(s2, pp); pp += NTHREADS;
        ISSUE1(s3, pp); pp += NTHREADS;
        ISSUE1(s4, pp); pp += NTHREADS;
        ISSUE1(s5, pp); pp += NTHREADS;
        int gend6 = ((ngrp - 6) / 6) * 6;   // steady iterations, multiple of 6
        int g = 0;
        for (; g < gend6; g += 6) {
            WAITV(5); CONSUME1(s0, g + 0); ISSUE1(s0, pp); pp += NTHREADS;
            WAITV(5); CONSUME1(s1, g + 1); ISSUE1(s1, pp); pp += NTHREADS;
            WAITV(5); CONSUME1(s2, g + 2); ISSUE1(s2, pp); pp += NTHREADS;
            WAITV(5); CONSUME1(s3, g + 3); ISSUE1(s3, pp); pp += NTHREADS;
            WAITV(5); CONSUME1(s4, g + 4); ISSUE1(s4, pp); pp += NTHREADS;
            WAITV(5); CONSUME1(s5, g + 5); ISSUE1(s5, pp); pp += NTHREADS;
        }
        WAITV(0);
        CONSUME1(s0, g + 0);
        CONSUME1(s1, g + 1);
        CONSUME1(s2, g + 2);
        CONSUME1(s3, g + 3);
        CONSUME1(s4, g + 4);
        CONSUME1(s5, g + 5);
        ring = g + 6;                        // groups consumed via ring
    }

    // remaining float4s + scalar tail (per-element, validated path)
    for (int i = ring * NTHREADS + tid; i < nvec; i += NTHREADS) {
        f4 a = v4[i];
        int e = head + (i << 2);
        push32(cand, cnt, ovf, a.x, e,     t, tbits);
        push32(cand, cnt, ovf, a.y, e + 1, t, tbits);
        push32(cand, cnt, ovf, a.z, e + 2, t, tbits);
        push32(cand, cnt, ovf, a.w, e + 3, t, tbits);
    }
    for (int i = head + (nvec << 2) + tid; i < V; i += NTHREADS)
        push32(cand, cnt, ovf, row[i], i, t, tbits);
}

__global__ __launch_bounds__(NTHREADS, 8)   // cap VGPR at 64 -> 8 waves/SIMD
void topk_jsd_kernel(const float* __restrict__ p, const float* __restrict__ q,
                     float* __restrict__ out, int V)
{
    __shared__ u64 candRaw[CAP];                 // u32 views: P = lo 4KB, Q = hi 4KB
    __shared__ u64 s_merge[4 * KTOP];
    __shared__ float s_f[8];
    __shared__ u32 s_c[4];
    __shared__ uint16_t topP[KTOP];
    __shared__ uint16_t topQ[KTOP];
    __shared__ uint16_t s_union[2 * KTOP];
    __shared__ int s_nu;

    u32* candP = (u32*)candRaw;
    u32* candQ = ((u32*)candRaw) + CAP;

    const int row = blockIdx.x;
    const int tid = threadIdx.x;
    const int lane = tid & 63, w = tid >> 6;
    const float* prow = p + (size_t)row * (size_t)V;
    const float* qrow = q + (size_t)row * (size_t)V;

    // ---- sample phase: max of first 2048 elems ----
    int smp = V < 2048 ? V : 2048;
    float msP = 0.f, msQ = 0.f;
    for (int i = tid; i < smp; i += NTHREADS) {
        msP = fmaxf(msP, prow[i]);
        msQ = fmaxf(msQ, qrow[i]);
    }
    float MsP = block_max(msP, s_f, tid);
    float MsQ = block_max(msQ, s_f, tid);

    float eps0 = fminf(128.f / (float)V + 1.f / (float)smp, 0.5f);
    float tP = MsP * (1.f - eps0);
    float tQ = MsQ * (1.f - eps0);
    u32 tPb = __float_as_uint(tP), tQb = __float_as_uint(tQ);

    if (tid == 0) { s_c[0] = 0; s_c[1] = 0; s_c[2] = 0; }
    __syncthreads();

    // ---- two sequential single-array streaming passes (VGPR-lean) ----
    stream_one(prow, V, tP, tPb, candP, &s_c[C_CNTP], &s_c[C_OVF], tid);
    stream_one(qrow, V, tQ, tQb, candQ, &s_c[C_CNTQ], &s_c[C_OVF], tid);

    __syncthreads();
    int ncP = (int)s_c[C_CNTP];
    int ncQ = (int)s_c[C_CNTQ];
    u32 ovf = s_c[C_OVF];
    __syncthreads();

    bool okP = !ovf && ncP >= KTOP && ncP <= CAP;
    bool okQ = !ovf && ncQ >= KTOP && ncQ <= CAP;

    // parallel single-wave extraction (non-destructive reads of cand LDS)
    if (okP && w == 0) {
        if (ncP <= 256) find32<4>(candP, ncP, topP, lane);
        else            find32<16>(candP, ncP, topP, lane);
    }
    if (okQ && w == 1) {
        if (ncQ <= 256) find32<4>(candQ, ncQ, topQ, lane);
        else            find32<16>(candQ, ncQ, topQ, lane);
    }

    // u64 fallback (validated path; overwrites candRaw)
    if (!okP) {
        float eps = eps0;
        int nc = collect_direct64(prow, V, MsP * (1.f - eps), candRaw, &s_c[C_GEN], tid);
        for (int a = 0; a < 10 && (nc < KTOP || nc > CAP); ++a) {
            eps = (nc > CAP) ? eps * 0.25f : fminf(eps * 4.f, 1.f);
            nc = collect_direct64(prow, V, MsP * (1.f - eps), candRaw, &s_c[C_GEN], tid);
        }
        if (nc > CAP) nc = CAP;
        find_topk64(candRaw, nc, topP, s_merge, tid);
    }
    if (!okQ) {
        float eps = eps0;
        int nc = collect_direct64(qrow, V, MsQ * (1.f - eps), candRaw, &s_c[C_GEN], tid);
        for (int a = 0; a < 10 && (nc < KTOP || nc > CAP); ++a) {
            eps = (nc > CAP) ? eps * 0.25f : fminf(eps * 4.f, 1.f);
            nc = collect_direct64(qrow, V, MsQ * (1.f - eps), candRaw, &s_c[C_GEN], tid);
        }
        if (nc > CAP) nc = CAP;
        find_topk64(candRaw, nc, topQ, s_merge, tid);
    }
    __syncthreads();

    // ---- union of index sets (wave 0) ----
    if (tid < KTOP) s_union[tid] = topP[tid];
    __syncthreads();
    if (tid < 64) {
        bool freshb = false; uint16_t qi = 0;
        if (tid < KTOP) {
            qi = topQ[tid]; freshb = true;
            for (int j = 0; j < KTOP; ++j) if (topP[j] == qi) freshb = false;
        }
        u64 mb = __ballot(freshb);
        int pos = __popcll(mb & ((1ull << tid) - 1ull));
        if (freshb) s_union[KTOP + pos] = qi;
        if (tid == 0) s_nu = KTOP + __popcll(mb);
    }
    __syncthreads();
    int nu = s_nu;

    // ---- gather union values (index clamp guards pathological fallbacks) ----
    float pv = 0.f, qv = 0.f;
    if (tid < nu) {
        int ui = s_union[tid]; ui = ui < V ? ui : V - 1;
        pv = prow[ui];
        qv = qrow[ui];
    }

    // ---- block-reduce masked sums ----
    float sp = pv, sq = qv;
    for (int off = 32; off; off >>= 1) { sp += __shfl_down(sp, off); sq += __shfl_down(sq, off); }
    if ((tid & 63) == 0) { s_f[w] = sp; s_f[4 + w] = sq; }
    __syncthreads();
    if (tid == 0) {
        float a = 0.f, b = 0.f;
        for (int ww = 0; ww < NTHREADS / 64; ++ww) { a += s_f[ww]; b += s_f[4 + ww]; }
        s_f[0] = a; s_f[4] = b;
    }
    __syncthreads();
    float sump = s_f[0], sumq = s_f[4];
    __syncthreads();

    // ---- JSD over union (identical formula to validated kernels) ----
    float term = 0.f;
    if (tid < nu) {
        float pn = pv / (sump + EPSV);
        float qn = qv / (sumq + EPSV);
        float mn = 0.5f * (pn + qn);
        float ps = pn + EPSV, qs = qn + EPSV, ms = mn + EPSV;
        term = 0.5f * (ps * logf(ps / ms) + qs * logf(qs / ms));
    }
    for (int off = 32; off; off >>= 1) term += __shfl_down(term, off);
    if ((tid & 63) == 0) s_f[w] = term;
    __syncthreads();
    if (tid == 0) {
        float a = 0.f;
        for (int ww = 0; ww < NTHREADS / 64; ++ww) a += s_f[ww];
        out[row] = a;
    }
}

extern "C" void kernel_launch(void* const* d_in, const int* in_sizes, int n_in,
                              void* d_out, int out_size, void* d_ws, size_t ws_size,
                              hipStream_t stream) {
    const float* p = (const float*)d_in[0];
    const float* q = (const float*)d_in[1];
    float* out = (float*)d_out;
    if (out_size <= 0) return;
    int N = out_size;            // B*S rows
    int V = in_sizes[0] / N;     // vocab size
    topk_jsd_kernel<<<dim3(N), dim3(NTHREADS), 0, stream>>>(p, q, out, V);
}